// Round 16
// baseline (299.030 us; speedup 1.0000x reference)
//
#include <hip/hip_runtime.h>

#define N_NODES 100000
#define N_EDGES 3200000
#define RPB 128
#define NB ((N_NODES + RPB - 1) / RPB)       // 782 buckets
#define SC_BLOCKS 288
#define SC_PER ((N_EDGES + SC_BLOCKS - 1) / SC_BLOCKS)   // 11112 edges/block
#define RS_CAP 6144                          // rowsort staging cap (max bucket ~4400)

typedef unsigned short ushort_t;
typedef unsigned int uint_t;

__device__ __forceinline__ ushort_t f32_to_bf16_rne(float f) {
    uint_t b = __float_as_uint(f);
    return (ushort_t)((b + 0x7FFFu + ((b >> 16) & 1u)) >> 16);
}
__device__ __forceinline__ float bf16_lo(uint_t u) {
    return __uint_as_float(u << 16);
}
__device__ __forceinline__ float bf16_hi(uint_t u) {
    return __uint_as_float(u & 0xffff0000u);
}

// ---------------- dense parts ----------------

__global__ void gemm_w12_kernel(const float* __restrict__ W1,
                                const float* __restrict__ W2,
                                float* __restrict__ W12) {
    int idx = blockIdx.x * blockDim.x + threadIdx.x;
    if (idx >= 32 * 128) return;
    int r = idx >> 7;
    int c = idx & 127;
    float acc = 0.f;
#pragma unroll
    for (int k = 0; k < 64; ++k) acc += W1[r * 64 + k] * W2[k * 128 + c];
    W12[idx] = acc;
}

__global__ void cvt_bf16_kernel(const float* __restrict__ in, ushort_t* __restrict__ ob) {
    int i = blockIdx.x * blockDim.x + threadIdx.x;
    if (i < N_NODES * 32) ob[i] = f32_to_bf16_rne(in[i]);
}

// out[r][jo:jo+4] = sum_k g2[r][k] * W12[k][jo:jo+4]  (R5-proven)
__global__ void gemm_out_kernel(const float* __restrict__ g2,
                                const float* __restrict__ W12,
                                float* __restrict__ out) {
    int tid = threadIdx.x;
    int jo = (tid & 31) * 4;
    int rl = tid >> 5;
    float4 w[32];
#pragma unroll
    for (int k = 0; k < 32; ++k) w[k] = *(const float4*)&W12[k * 128 + jo];
    for (int r = blockIdx.x * 8 + rl; r < N_NODES; r += gridDim.x * 8) {
        const float4* g4 = (const float4*)(g2 + (size_t)r * 32);
        float4 acc = make_float4(0.f, 0.f, 0.f, 0.f);
#pragma unroll
        for (int q = 0; q < 8; ++q) {
            float4 gv = g4[q];
            int k = q * 4;
            acc.x += gv.x * w[k].x;     acc.y += gv.x * w[k].y;
            acc.z += gv.x * w[k].z;     acc.w += gv.x * w[k].w;
            acc.x += gv.y * w[k + 1].x; acc.y += gv.y * w[k + 1].y;
            acc.z += gv.y * w[k + 1].z; acc.w += gv.y * w[k + 1].w;
            acc.x += gv.z * w[k + 2].x; acc.y += gv.z * w[k + 2].y;
            acc.z += gv.z * w[k + 2].z; acc.w += gv.z * w[k + 2].w;
            acc.x += gv.w * w[k + 3].x; acc.y += gv.w * w[k + 3].y;
            acc.z += gv.w * w[k + 3].z; acc.w += gv.w * w[k + 3].w;
        }
        *(float4*)&out[(size_t)r * 128 + jo] = acc;
    }
}

// ---------------- bucket-level hist + scan ----------------

__global__ void hist_bucket_kernel(const int* __restrict__ row, int* __restrict__ cnt) {
    __shared__ int h[NB];
    for (int t = threadIdx.x; t < NB; t += blockDim.x) h[t] = 0;
    __syncthreads();
    int per = (N_EDGES + gridDim.x - 1) / gridDim.x;
    int s = blockIdx.x * per;
    int e = min(s + per, N_EDGES);
    for (int i = s + threadIdx.x; i < e; i += blockDim.x)
        atomicAdd(&h[row[i] >> 7], 1);
    __syncthreads();
    for (int t = threadIdx.x; t < NB; t += blockDim.x)
        if (h[t]) atomicAdd(&cnt[t], h[t]);
}

__global__ void scan_bucket_kernel(const int* __restrict__ cnt,
                                   int* __restrict__ offs, int* __restrict__ cur_b) {
    __shared__ int s[1024];
    int t = threadIdx.x;
    int v = (t < NB) ? cnt[t] : 0;
    s[t] = v;
    __syncthreads();
    for (int off = 1; off < 1024; off <<= 1) {
        int add = (t >= off) ? s[t - off] : 0;
        __syncthreads();
        s[t] += add;
        __syncthreads();
    }
    if (t < NB) { int x = s[t] - v; offs[t] = x; cur_b[t] = x; }
    if (t == 0) offs[NB] = N_EDGES;
}

// ---------------- hop-1: LDS-payload bucket scatter (R13-proven) ----------------
__global__ void __launch_bounds__(1024, 1)
scatter_stage_kernel(const int* __restrict__ row, const int* __restrict__ col,
                     const float* __restrict__ val,
                     int* __restrict__ cur_b, int2* __restrict__ ebuf) {
    __shared__ int2 payload[SC_PER];
    __shared__ ushort_t bkt[SC_PER];
    __shared__ int h[NB];
    __shared__ int lbase[NB];
    __shared__ int gbase[NB];
    __shared__ int scan_s[1024];
    int t = threadIdx.x;
    int s = blockIdx.x * SC_PER;
    int e = min(s + SC_PER, N_EDGES);
    int n = e - s;
    for (int i = t; i < NB; i += 1024) h[i] = 0;
    __syncthreads();
    for (int i = t; i < n; i += 1024) atomicAdd(&h[row[s + i] >> 7], 1);
    __syncthreads();
    int v = (t < NB) ? h[t] : 0;
    scan_s[t] = v;
    __syncthreads();
    for (int off = 1; off < 1024; off <<= 1) {
        int add = (t >= off) ? scan_s[t - off] : 0;
        __syncthreads();
        scan_s[t] += add;
        __syncthreads();
    }
    if (t < NB) {
        lbase[t] = scan_s[t] - v;
        gbase[t] = v ? atomicAdd(&cur_b[t], v) : 0;
        h[t] = 0;
    }
    __syncthreads();
    for (int i = t; i < n; i += 1024) {
        int r = row[s + i];
        int b = r >> 7;
        int lp = atomicAdd(&h[b], 1);
        int slot = lbase[b] + lp;
        payload[slot] = make_int2((col[s + i] << 7) | (r & 127), __float_as_int(val[s + i]));
        bkt[slot] = (ushort_t)b;
    }
    __syncthreads();
    for (int i = t; i < n; i += 1024) {
        int b = bkt[i];
        ebuf[gbase[b] + (i - lbase[b])] = payload[i];
    }
}

// ---------------- hop-2: perm-staged rowsort (512 thr, R13-proven); writes rs ----------------
__global__ void rowsort_stage_kernel(const int* __restrict__ offs, const int2* __restrict__ ebuf,
                                     int2* __restrict__ ep, int* __restrict__ rs) {
    __shared__ int h[RPB];
    __shared__ int loff[RPB];
    __shared__ int curl[RPB];
    __shared__ ushort_t perm[RS_CAP];
    int b = blockIdx.x;
    int s = offs[b], e = offs[b + 1];
    int n = e - s;
    int t = threadIdx.x;
    if (t < RPB) h[t] = 0;
    __syncthreads();
    for (int i = t; i < n; i += blockDim.x)
        atomicAdd(&h[ebuf[s + i].x & 127], 1);
    __syncthreads();
    if (t < RPB) loff[t] = h[t];
    __syncthreads();
    for (int off = 1; off < RPB; off <<= 1) {
        int add = (t < RPB && t >= off) ? loff[t - off] : 0;
        __syncthreads();
        if (t < RPB) loff[t] += add;
        __syncthreads();
    }
    if (t < RPB) {
        int excl = loff[t] - h[t];
        curl[t] = excl;
        int r = b * RPB + t;
        if (r < N_NODES) rs[r] = s + excl;
    }
    if (b == 0 && t == 0) rs[N_NODES] = N_EDGES;
    __syncthreads();
    if (n <= RS_CAP) {
        for (int i = t; i < n; i += blockDim.x) {
            int rl = ebuf[s + i].x & 127;
            int lp = atomicAdd(&curl[rl], 1);
            perm[lp] = (ushort_t)i;
        }
        __syncthreads();
        for (int i = t; i < n; i += blockDim.x) {
            int2 cv = ebuf[s + perm[i]];
            ep[s + i] = make_int2(cv.x >> 7, cv.y);   // {col, valbits}, coalesced
        }
    } else {
        for (int i = t; i < n; i += blockDim.x) {
            int2 cv = ebuf[s + i];
            int rl = cv.x & 127;
            int pos = s + atomicAdd(&curl[rl], 1);
            ep[pos] = make_int2(cv.x >> 7, cv.y);
        }
    }
}

// ---------------- CSR SpMM: 2 bf16 feats/lane, 4 edge-groups, 8-deep ----------------
// NEW vs R13: ep stream read via nontemporal loads to protect the 6.4MB
// gather table's L2 residency. Otherwise identical.
template <bool OUT_BF16>
__global__ void spmm_csr_kernel(const int* __restrict__ rs,
                                const long long* __restrict__ ep,
                                const uint_t* __restrict__ xb,
                                void* __restrict__ outv) {
    int gid = blockIdx.x * blockDim.x + threadIdx.x;
    int wid = gid >> 6;
    int nwaves = (gridDim.x * blockDim.x) >> 6;
    int lane = threadIdx.x & 63;
    int j2 = lane & 15;
    int g = lane >> 4;
    for (int r = wid; r < N_NODES; r += nwaves) {
        int s = rs[r], e = rs[r + 1];
        float a0 = 0.f, a1 = 0.f, b0 = 0.f, b1 = 0.f;
        int p = s + g;
        for (; p + 28 < e; p += 32) {
            long long v0 = __builtin_nontemporal_load(ep + p);
            long long v1 = __builtin_nontemporal_load(ep + p + 4);
            long long v2 = __builtin_nontemporal_load(ep + p + 8);
            long long v3 = __builtin_nontemporal_load(ep + p + 12);
            long long v4 = __builtin_nontemporal_load(ep + p + 16);
            long long v5 = __builtin_nontemporal_load(ep + p + 20);
            long long v6 = __builtin_nontemporal_load(ep + p + 24);
            long long v7 = __builtin_nontemporal_load(ep + p + 28);
            uint_t u0 = xb[(int)(v0 & 0xffffffffLL) * 16 + j2];
            uint_t u1 = xb[(int)(v1 & 0xffffffffLL) * 16 + j2];
            uint_t u2 = xb[(int)(v2 & 0xffffffffLL) * 16 + j2];
            uint_t u3 = xb[(int)(v3 & 0xffffffffLL) * 16 + j2];
            uint_t u4 = xb[(int)(v4 & 0xffffffffLL) * 16 + j2];
            uint_t u5 = xb[(int)(v5 & 0xffffffffLL) * 16 + j2];
            uint_t u6 = xb[(int)(v6 & 0xffffffffLL) * 16 + j2];
            uint_t u7 = xb[(int)(v7 & 0xffffffffLL) * 16 + j2];
            float w0 = __int_as_float((int)(v0 >> 32));
            float w1 = __int_as_float((int)(v1 >> 32));
            float w2 = __int_as_float((int)(v2 >> 32));
            float w3 = __int_as_float((int)(v3 >> 32));
            float w4 = __int_as_float((int)(v4 >> 32));
            float w5 = __int_as_float((int)(v5 >> 32));
            float w6 = __int_as_float((int)(v6 >> 32));
            float w7 = __int_as_float((int)(v7 >> 32));
            a0 += w0 * bf16_lo(u0); a1 += w0 * bf16_hi(u0);
            b0 += w1 * bf16_lo(u1); b1 += w1 * bf16_hi(u1);
            a0 += w2 * bf16_lo(u2); a1 += w2 * bf16_hi(u2);
            b0 += w3 * bf16_lo(u3); b1 += w3 * bf16_hi(u3);
            a0 += w4 * bf16_lo(u4); a1 += w4 * bf16_hi(u4);
            b0 += w5 * bf16_lo(u5); b1 += w5 * bf16_hi(u5);
            a0 += w6 * bf16_lo(u6); a1 += w6 * bf16_hi(u6);
            b0 += w7 * bf16_lo(u7); b1 += w7 * bf16_hi(u7);
        }
        for (; p < e; p += 4) {
            long long v = __builtin_nontemporal_load(ep + p);
            uint_t u = xb[(int)(v & 0xffffffffLL) * 16 + j2];
            float w = __int_as_float((int)(v >> 32));
            a0 += w * bf16_lo(u);
            a1 += w * bf16_hi(u);
        }
        float r0 = a0 + b0;
        float r1 = a1 + b1;
        r0 += __shfl_xor(r0, 16, 64);
        r0 += __shfl_xor(r0, 32, 64);
        r1 += __shfl_xor(r1, 16, 64);
        r1 += __shfl_xor(r1, 32, 64);
        if (g == 0) {
            if constexpr (OUT_BF16) {
                uint_t pk = (uint_t)f32_to_bf16_rne(r0) | ((uint_t)f32_to_bf16_rne(r1) << 16);
                ((uint_t*)outv)[r * 16 + j2] = pk;
            } else {
                ((float2*)outv)[r * 16 + j2] = make_float2(r0, r1);
            }
        }
    }
}

// ---------------- fallback path (fp32 throughout) ----------------
__global__ void spmm32_atomic_kernel(const int* __restrict__ row,
                                     const int* __restrict__ col,
                                     const float* __restrict__ val,
                                     const float* __restrict__ x,
                                     float* __restrict__ out) {
    int id = blockIdx.x * blockDim.x + threadIdx.x;
    int e = id >> 5;
    int j = id & 31;
    if (e >= N_EDGES) return;
    atomicAdd(&out[row[e] * 32 + j], val[e] * x[col[e] * 32 + j]);
}

__global__ void gemm_out_fallback_kernel(const float* __restrict__ g2,
                                         const float* __restrict__ W12,
                                         float* __restrict__ out) {
    int id = blockIdx.x * blockDim.x + threadIdx.x;
    int i = id >> 7;
    int j = id & 127;
    const float* g = g2 + i * 32;
    float acc = 0.f;
#pragma unroll
    for (int k = 0; k < 32; ++k) acc += g[k] * W12[k * 128 + j];
    out[id] = acc;
}

extern "C" void kernel_launch(void* const* d_in, const int* in_sizes, int n_in,
                              void* d_out, int out_size, void* d_ws, size_t ws_size,
                              hipStream_t stream) {
    const float* feat = (const float*)d_in[0];   // [N, 32]
    const float* W1   = (const float*)d_in[1];   // [32, 64]
    const float* W2   = (const float*)d_in[2];   // [64, 128]
    const int*   erow = (const int*)d_in[3];     // [E]
    const int*   ecol = (const int*)d_in[4];     // [E]
    const float* eval_= (const float*)d_in[5];   // [E]
    float* out = (float*)d_out;                  // [N, 128]

    // ws: W12[4096 f32] | xb[N*32 bf16] | g1b[N*32 bf16] | g2[N*32 f32] |
    //     ep[E int2] | cnt[NB] | offs[NB+1] | cur_b[NB] | rs[N+2]
    float*    W12   = (float*)d_ws;
    ushort_t* xb    = (ushort_t*)(W12 + 4096);
    ushort_t* g1b   = xb + (size_t)N_NODES * 32;
    float*    g2    = (float*)(g1b + (size_t)N_NODES * 32);
    int2*     ep    = (int2*)(g2 + (size_t)N_NODES * 32);
    int*      cnt   = (int*)(ep + N_EDGES);
    int*      offs  = cnt + NB;
    int*      cur_b = offs + NB + 1;
    int*      rs    = cur_b + NB;
    size_t    needed = (size_t)((char*)(rs + N_NODES + 2) - (char*)d_ws);

    // bucket-grouped intermediate lives in d_out (25.6MB <= 51.2MB), fully
    // consumed by rowsort before gemm_out overwrites d_out.
    int2* ebuf = (int2*)d_out;

    gemm_w12_kernel<<<16, 256, 0, stream>>>(W1, W2, W12);

    if (ws_size >= needed) {
        cvt_bf16_kernel<<<(N_NODES * 32 + 255) / 256, 256, 0, stream>>>(feat, xb);

        hipMemsetAsync(cnt, 0, NB * sizeof(int), stream);
        hist_bucket_kernel<<<256, 1024, 0, stream>>>(erow, cnt);
        scan_bucket_kernel<<<1, 1024, 0, stream>>>(cnt, offs, cur_b);
        scatter_stage_kernel<<<SC_BLOCKS, 1024, 0, stream>>>(erow, ecol, eval_, cur_b, ebuf);
        rowsort_stage_kernel<<<NB, 512, 0, stream>>>(offs, ebuf, ep, rs);

        const long long* epl = (const long long*)ep;
        spmm_csr_kernel<true><<<2048, 256, 0, stream>>>(rs, epl, (const uint_t*)xb, g1b);
        spmm_csr_kernel<false><<<2048, 256, 0, stream>>>(rs, epl, (const uint_t*)g1b, g2);

        gemm_out_kernel<<<1024, 256, 0, stream>>>(g2, W12, out);
    } else {
        // fallback: fp32 atomic path
        float* g1f = (float*)d_ws + 4096;
        float* g2f = g1f + (size_t)N_NODES * 32;
        hipMemsetAsync(g1f, 0, (size_t)N_NODES * 32 * 2 * sizeof(float), stream);
        spmm32_atomic_kernel<<<(N_EDGES * 32) / 256, 256, 0, stream>>>(erow, ecol, eval_, feat, g1f);
        spmm32_atomic_kernel<<<(N_EDGES * 32) / 256, 256, 0, stream>>>(erow, ecol, eval_, g1f, g2f);
        gemm_out_fallback_kernel<<<(N_NODES * 128) / 256, 256, 0, stream>>>(g2f, W12, out);
    }
}

// Round 17
// 262.087 us; speedup vs baseline: 1.1410x; 1.1410x over previous
//
#include <hip/hip_runtime.h>

#define N_NODES 100000
#define N_EDGES 3200000
#define RPB 128
#define NB ((N_NODES + RPB - 1) / RPB)       // 782 buckets
#define SC_BLOCKS 288
#define SC_PER ((N_EDGES + SC_BLOCKS - 1) / SC_BLOCKS)   // 11112 edges/block
#define RS_CAP 6144                          // rowsort staging cap (max bucket ~4400)

typedef unsigned short ushort_t;
typedef unsigned int uint_t;

__device__ __forceinline__ ushort_t f32_to_bf16_rne(float f) {
    uint_t b = __float_as_uint(f);
    return (ushort_t)((b + 0x7FFFu + ((b >> 16) & 1u)) >> 16);
}
__device__ __forceinline__ float bf16_lo(uint_t u) {
    return __uint_as_float(u << 16);
}
__device__ __forceinline__ float bf16_hi(uint_t u) {
    return __uint_as_float(u & 0xffff0000u);
}

// ---------------- dense parts ----------------

__global__ void gemm_w12_kernel(const float* __restrict__ W1,
                                const float* __restrict__ W2,
                                float* __restrict__ W12) {
    int idx = blockIdx.x * blockDim.x + threadIdx.x;
    if (idx >= 32 * 128) return;
    int r = idx >> 7;
    int c = idx & 127;
    float acc = 0.f;
#pragma unroll
    for (int k = 0; k < 64; ++k) acc += W1[r * 64 + k] * W2[k * 128 + c];
    W12[idx] = acc;
}

__global__ void cvt_bf16_kernel(const float* __restrict__ in, ushort_t* __restrict__ ob) {
    int i = blockIdx.x * blockDim.x + threadIdx.x;
    if (i < N_NODES * 32) ob[i] = f32_to_bf16_rne(in[i]);
}

// out[r][jo:jo+4] = sum_k g2[r][k] * W12[k][jo:jo+4]  (R5-proven)
__global__ void gemm_out_kernel(const float* __restrict__ g2,
                                const float* __restrict__ W12,
                                float* __restrict__ out) {
    int tid = threadIdx.x;
    int jo = (tid & 31) * 4;
    int rl = tid >> 5;
    float4 w[32];
#pragma unroll
    for (int k = 0; k < 32; ++k) w[k] = *(const float4*)&W12[k * 128 + jo];
    for (int r = blockIdx.x * 8 + rl; r < N_NODES; r += gridDim.x * 8) {
        const float4* g4 = (const float4*)(g2 + (size_t)r * 32);
        float4 acc = make_float4(0.f, 0.f, 0.f, 0.f);
#pragma unroll
        for (int q = 0; q < 8; ++q) {
            float4 gv = g4[q];
            int k = q * 4;
            acc.x += gv.x * w[k].x;     acc.y += gv.x * w[k].y;
            acc.z += gv.x * w[k].z;     acc.w += gv.x * w[k].w;
            acc.x += gv.y * w[k + 1].x; acc.y += gv.y * w[k + 1].y;
            acc.z += gv.y * w[k + 1].z; acc.w += gv.y * w[k + 1].w;
            acc.x += gv.z * w[k + 2].x; acc.y += gv.z * w[k + 2].y;
            acc.z += gv.z * w[k + 2].z; acc.w += gv.z * w[k + 2].w;
            acc.x += gv.w * w[k + 3].x; acc.y += gv.w * w[k + 3].y;
            acc.z += gv.w * w[k + 3].z; acc.w += gv.w * w[k + 3].w;
        }
        *(float4*)&out[(size_t)r * 128 + jo] = acc;
    }
}

// ---------------- bucket-level hist + scan ----------------

__global__ void hist_bucket_kernel(const int* __restrict__ row, int* __restrict__ cnt) {
    __shared__ int h[NB];
    for (int t = threadIdx.x; t < NB; t += blockDim.x) h[t] = 0;
    __syncthreads();
    int per = (N_EDGES + gridDim.x - 1) / gridDim.x;
    int s = blockIdx.x * per;
    int e = min(s + per, N_EDGES);
    for (int i = s + threadIdx.x; i < e; i += blockDim.x)
        atomicAdd(&h[row[i] >> 7], 1);
    __syncthreads();
    for (int t = threadIdx.x; t < NB; t += blockDim.x)
        if (h[t]) atomicAdd(&cnt[t], h[t]);
}

__global__ void scan_bucket_kernel(const int* __restrict__ cnt,
                                   int* __restrict__ offs, int* __restrict__ cur_b) {
    __shared__ int s[1024];
    int t = threadIdx.x;
    int v = (t < NB) ? cnt[t] : 0;
    s[t] = v;
    __syncthreads();
    for (int off = 1; off < 1024; off <<= 1) {
        int add = (t >= off) ? s[t - off] : 0;
        __syncthreads();
        s[t] += add;
        __syncthreads();
    }
    if (t < NB) { int x = s[t] - v; offs[t] = x; cur_b[t] = x; }
    if (t == 0) offs[NB] = N_EDGES;
}

// ---------------- hop-1: LDS-payload bucket scatter (R13-proven) ----------------
__global__ void __launch_bounds__(1024, 1)
scatter_stage_kernel(const int* __restrict__ row, const int* __restrict__ col,
                     const float* __restrict__ val,
                     int* __restrict__ cur_b, int2* __restrict__ ebuf) {
    __shared__ int2 payload[SC_PER];
    __shared__ ushort_t bkt[SC_PER];
    __shared__ int h[NB];
    __shared__ int lbase[NB];
    __shared__ int gbase[NB];
    __shared__ int scan_s[1024];
    int t = threadIdx.x;
    int s = blockIdx.x * SC_PER;
    int e = min(s + SC_PER, N_EDGES);
    int n = e - s;
    for (int i = t; i < NB; i += 1024) h[i] = 0;
    __syncthreads();
    for (int i = t; i < n; i += 1024) atomicAdd(&h[row[s + i] >> 7], 1);
    __syncthreads();
    int v = (t < NB) ? h[t] : 0;
    scan_s[t] = v;
    __syncthreads();
    for (int off = 1; off < 1024; off <<= 1) {
        int add = (t >= off) ? scan_s[t - off] : 0;
        __syncthreads();
        scan_s[t] += add;
        __syncthreads();
    }
    if (t < NB) {
        lbase[t] = scan_s[t] - v;
        gbase[t] = v ? atomicAdd(&cur_b[t], v) : 0;
        h[t] = 0;
    }
    __syncthreads();
    for (int i = t; i < n; i += 1024) {
        int r = row[s + i];
        int b = r >> 7;
        int lp = atomicAdd(&h[b], 1);
        int slot = lbase[b] + lp;
        payload[slot] = make_int2((col[s + i] << 7) | (r & 127), __float_as_int(val[s + i]));
        bkt[slot] = (ushort_t)b;
    }
    __syncthreads();
    for (int i = t; i < n; i += 1024) {
        int b = bkt[i];
        ebuf[gbase[b] + (i - lbase[b])] = payload[i];
    }
}

// ---------------- hop-2: perm-staged rowsort (512 thr, R13-proven); writes rs ----------------
__global__ void rowsort_stage_kernel(const int* __restrict__ offs, const int2* __restrict__ ebuf,
                                     int2* __restrict__ ep, int* __restrict__ rs) {
    __shared__ int h[RPB];
    __shared__ int loff[RPB];
    __shared__ int curl[RPB];
    __shared__ ushort_t perm[RS_CAP];
    int b = blockIdx.x;
    int s = offs[b], e = offs[b + 1];
    int n = e - s;
    int t = threadIdx.x;
    if (t < RPB) h[t] = 0;
    __syncthreads();
    for (int i = t; i < n; i += blockDim.x)
        atomicAdd(&h[ebuf[s + i].x & 127], 1);
    __syncthreads();
    if (t < RPB) loff[t] = h[t];
    __syncthreads();
    for (int off = 1; off < RPB; off <<= 1) {
        int add = (t < RPB && t >= off) ? loff[t - off] : 0;
        __syncthreads();
        if (t < RPB) loff[t] += add;
        __syncthreads();
    }
    if (t < RPB) {
        int excl = loff[t] - h[t];
        curl[t] = excl;
        int r = b * RPB + t;
        if (r < N_NODES) rs[r] = s + excl;
    }
    if (b == 0 && t == 0) rs[N_NODES] = N_EDGES;
    __syncthreads();
    if (n <= RS_CAP) {
        for (int i = t; i < n; i += blockDim.x) {
            int rl = ebuf[s + i].x & 127;
            int lp = atomicAdd(&curl[rl], 1);
            perm[lp] = (ushort_t)i;
        }
        __syncthreads();
        for (int i = t; i < n; i += blockDim.x) {
            int2 cv = ebuf[s + perm[i]];
            ep[s + i] = make_int2(cv.x >> 7, cv.y);   // {col, valbits}, coalesced
        }
    } else {
        for (int i = t; i < n; i += blockDim.x) {
            int2 cv = ebuf[s + i];
            int rl = cv.x & 127;
            int pos = s + atomicAdd(&curl[rl], 1);
            ep[pos] = make_int2(cv.x >> 7, cv.y);
        }
    }
}

// ---------------- CSR SpMM: 2 bf16 feats/lane, 4 edge-groups, 8-deep (R10/R13-proven) ----------------
template <bool OUT_BF16>
__global__ void spmm_csr_kernel(const int* __restrict__ rs,
                                const int2* __restrict__ ep,
                                const uint_t* __restrict__ xb,
                                void* __restrict__ outv) {
    int gid = blockIdx.x * blockDim.x + threadIdx.x;
    int wid = gid >> 6;
    int nwaves = (gridDim.x * blockDim.x) >> 6;
    int lane = threadIdx.x & 63;
    int j2 = lane & 15;
    int g = lane >> 4;
    for (int r = wid; r < N_NODES; r += nwaves) {
        int s = rs[r], e = rs[r + 1];
        float a0 = 0.f, a1 = 0.f, b0 = 0.f, b1 = 0.f;
        int p = s + g;
        for (; p + 28 < e; p += 32) {
            int2 c0 = ep[p];
            int2 c1 = ep[p + 4];
            int2 c2 = ep[p + 8];
            int2 c3 = ep[p + 12];
            int2 c4 = ep[p + 16];
            int2 c5 = ep[p + 20];
            int2 c6 = ep[p + 24];
            int2 c7 = ep[p + 28];
            uint_t u0 = xb[c0.x * 16 + j2];
            uint_t u1 = xb[c1.x * 16 + j2];
            uint_t u2 = xb[c2.x * 16 + j2];
            uint_t u3 = xb[c3.x * 16 + j2];
            uint_t u4 = xb[c4.x * 16 + j2];
            uint_t u5 = xb[c5.x * 16 + j2];
            uint_t u6 = xb[c6.x * 16 + j2];
            uint_t u7 = xb[c7.x * 16 + j2];
            float w0 = __int_as_float(c0.y);
            float w1 = __int_as_float(c1.y);
            float w2 = __int_as_float(c2.y);
            float w3 = __int_as_float(c3.y);
            float w4 = __int_as_float(c4.y);
            float w5 = __int_as_float(c5.y);
            float w6 = __int_as_float(c6.y);
            float w7 = __int_as_float(c7.y);
            a0 += w0 * bf16_lo(u0); a1 += w0 * bf16_hi(u0);
            b0 += w1 * bf16_lo(u1); b1 += w1 * bf16_hi(u1);
            a0 += w2 * bf16_lo(u2); a1 += w2 * bf16_hi(u2);
            b0 += w3 * bf16_lo(u3); b1 += w3 * bf16_hi(u3);
            a0 += w4 * bf16_lo(u4); a1 += w4 * bf16_hi(u4);
            b0 += w5 * bf16_lo(u5); b1 += w5 * bf16_hi(u5);
            a0 += w6 * bf16_lo(u6); a1 += w6 * bf16_hi(u6);
            b0 += w7 * bf16_lo(u7); b1 += w7 * bf16_hi(u7);
        }
        for (; p < e; p += 4) {
            int2 cv = ep[p];
            uint_t u = xb[cv.x * 16 + j2];
            float w = __int_as_float(cv.y);
            a0 += w * bf16_lo(u);
            a1 += w * bf16_hi(u);
        }
        float r0 = a0 + b0;
        float r1 = a1 + b1;
        r0 += __shfl_xor(r0, 16, 64);
        r0 += __shfl_xor(r0, 32, 64);
        r1 += __shfl_xor(r1, 16, 64);
        r1 += __shfl_xor(r1, 32, 64);
        if (g == 0) {
            if constexpr (OUT_BF16) {
                uint_t pk = (uint_t)f32_to_bf16_rne(r0) | ((uint_t)f32_to_bf16_rne(r1) << 16);
                ((uint_t*)outv)[r * 16 + j2] = pk;
            } else {
                ((float2*)outv)[r * 16 + j2] = make_float2(r0, r1);
            }
        }
    }
}

// ---------------- fallback path (fp32 throughout) ----------------
__global__ void spmm32_atomic_kernel(const int* __restrict__ row,
                                     const int* __restrict__ col,
                                     const float* __restrict__ val,
                                     const float* __restrict__ x,
                                     float* __restrict__ out) {
    int id = blockIdx.x * blockDim.x + threadIdx.x;
    int e = id >> 5;
    int j = id & 31;
    if (e >= N_EDGES) return;
    atomicAdd(&out[row[e] * 32 + j], val[e] * x[col[e] * 32 + j]);
}

__global__ void gemm_out_fallback_kernel(const float* __restrict__ g2,
                                         const float* __restrict__ W12,
                                         float* __restrict__ out) {
    int id = blockIdx.x * blockDim.x + threadIdx.x;
    int i = id >> 7;
    int j = id & 127;
    const float* g = g2 + i * 32;
    float acc = 0.f;
#pragma unroll
    for (int k = 0; k < 32; ++k) acc += g[k] * W12[k * 128 + j];
    out[id] = acc;
}

extern "C" void kernel_launch(void* const* d_in, const int* in_sizes, int n_in,
                              void* d_out, int out_size, void* d_ws, size_t ws_size,
                              hipStream_t stream) {
    const float* feat = (const float*)d_in[0];   // [N, 32]
    const float* W1   = (const float*)d_in[1];   // [32, 64]
    const float* W2   = (const float*)d_in[2];   // [64, 128]
    const int*   erow = (const int*)d_in[3];     // [E]
    const int*   ecol = (const int*)d_in[4];     // [E]
    const float* eval_= (const float*)d_in[5];   // [E]
    float* out = (float*)d_out;                  // [N, 128]

    // ws: W12[4096 f32] | xb[N*32 bf16] | g1b[N*32 bf16] | g2[N*32 f32] |
    //     ep[E int2] | cnt[NB] | offs[NB+1] | cur_b[NB] | rs[N+2]
    float*    W12   = (float*)d_ws;
    ushort_t* xb    = (ushort_t*)(W12 + 4096);
    ushort_t* g1b   = xb + (size_t)N_NODES * 32;
    float*    g2    = (float*)(g1b + (size_t)N_NODES * 32);
    int2*     ep    = (int2*)(g2 + (size_t)N_NODES * 32);
    int*      cnt   = (int*)(ep + N_EDGES);
    int*      offs  = cnt + NB;
    int*      cur_b = offs + NB + 1;
    int*      rs    = cur_b + NB;
    size_t    needed = (size_t)((char*)(rs + N_NODES + 2) - (char*)d_ws);

    // bucket-grouped intermediate lives in d_out (25.6MB <= 51.2MB), fully
    // consumed by rowsort before gemm_out overwrites d_out.
    int2* ebuf = (int2*)d_out;

    gemm_w12_kernel<<<16, 256, 0, stream>>>(W1, W2, W12);

    if (ws_size >= needed) {
        cvt_bf16_kernel<<<(N_NODES * 32 + 255) / 256, 256, 0, stream>>>(feat, xb);

        hipMemsetAsync(cnt, 0, NB * sizeof(int), stream);
        hist_bucket_kernel<<<256, 1024, 0, stream>>>(erow, cnt);
        scan_bucket_kernel<<<1, 1024, 0, stream>>>(cnt, offs, cur_b);
        scatter_stage_kernel<<<SC_BLOCKS, 1024, 0, stream>>>(erow, ecol, eval_, cur_b, ebuf);
        rowsort_stage_kernel<<<NB, 512, 0, stream>>>(offs, ebuf, ep, rs);

        spmm_csr_kernel<true><<<2048, 256, 0, stream>>>(rs, ep, (const uint_t*)xb, g1b);
        spmm_csr_kernel<false><<<2048, 256, 0, stream>>>(rs, ep, (const uint_t*)g1b, g2);

        gemm_out_kernel<<<1024, 256, 0, stream>>>(g2, W12, out);
    } else {
        // fallback: fp32 atomic path
        float* g1f = (float*)d_ws + 4096;
        float* g2f = g1f + (size_t)N_NODES * 32;
        hipMemsetAsync(g1f, 0, (size_t)N_NODES * 32 * 2 * sizeof(float), stream);
        spmm32_atomic_kernel<<<(N_EDGES * 32) / 256, 256, 0, stream>>>(erow, ecol, eval_, feat, g1f);
        spmm32_atomic_kernel<<<(N_EDGES * 32) / 256, 256, 0, stream>>>(erow, ecol, eval_, g1f, g2f);
        gemm_out_fallback_kernel<<<(N_NODES * 128) / 256, 256, 0, stream>>>(g2f, W12, out);
    }
}